// Round 10
// baseline (439.405 us; speedup 1.0000x reference)
//
#include <hip/hip_runtime.h>

typedef unsigned short u16;
typedef unsigned int u32;

#define HNUM 16
#define NSEQ 4096
#define CDIM 1024
#define SCALE 0.125f
#define LOG2E 1.4426950408889634f

using bf16x8 = __attribute__((ext_vector_type(8))) __bf16;
using f32x4  = __attribute__((ext_vector_type(4))) float;
using u32x4  = __attribute__((ext_vector_type(4))) u32;

__device__ __forceinline__ u16 f2bf(float f) {
  union { float f; u32 u; } v; v.f = f;
  u32 u = v.u;
  return (u16)((u + 0x7fffu + ((u >> 16) & 1u)) >> 16);
}
__device__ __forceinline__ float fexp2(float x) { return __builtin_amdgcn_exp2f(x); }

__device__ __forceinline__ f32x4 mfma16(bf16x8 a, bf16x8 b, f32x4 c) {
  return __builtin_amdgcn_mfma_f32_16x16x32_bf16(a, b, c, 0, 0, 0);
}

// pack 2 f32 -> 1 dword of 2 bf16 (round-half-up): lo16=bf(a), hi16=bf(b)
__device__ __forceinline__ u32 pack2(float a, float b) {
  union { float f; u32 u; } A, B;
  A.f = a; B.f = b;
  return __builtin_amdgcn_perm(B.u + 0x8000u, A.u + 0x8000u, 0x07060302u);
}

// async global->LDS, 16B/lane; LDS dest = wave-uniform base + lane*16
__device__ __forceinline__ void g2l16(const void* g, void* l) {
  __builtin_amdgcn_global_load_lds(
      (const __attribute__((address_space(1))) unsigned int*)(unsigned long long)g,
      (__attribute__((address_space(3))) unsigned int*)(unsigned int)(unsigned long long)l,
      16, 0, 0);
}

// ---- merged prep kernel: x1 cvt + 3 convert-transposes, range-dispatched ----
__device__ __forceinline__ void cvtT_body(const float* __restrict__ in,
                                          u16* __restrict__ out, int R, int C,
                                          int bx, int by, float scale, int tid) {
  __shared__ u16 t[64][65];
  const int r0 = by * 64, c0 = bx * 64;
  const int tr = tid >> 2, tc = (tid & 3) * 16;
  const float* src = in + (r0 + tr) * C + c0 + tc;
#pragma unroll
  for (int i = 0; i < 16; ++i) t[tr][tc + i] = f2bf(src[i] * scale);
  __syncthreads();
  u16* dst = out + (c0 + tr) * R + r0 + tc;
#pragma unroll
  for (int i = 0; i < 16; ++i) dst[i] = t[tc + i][tr];
}

// blocks: [0,2048) x1 cvt | [2048,2560) Wqkv T | [2560,2816) Wproj T | [2816,3840) x2 T
__global__ __launch_bounds__(256) void prep_k(const float* __restrict__ x1,
                                              u16* __restrict__ x1b,
                                              const float* __restrict__ Wqkv,
                                              u16* __restrict__ WqT,
                                              const float* __restrict__ Wproj,
                                              u16* __restrict__ WpT,
                                              const float* __restrict__ x2,
                                              u16* __restrict__ Vt,
                                              float cfac) {
  const int b = blockIdx.x, tid = threadIdx.x;
  if (b < 2048) {
    const int i = (b * 256 + tid) * 8;
    const float4 f0 = *(const float4*)(x1 + i);
    const float4 f1 = *(const float4*)(x1 + i + 4);
    u32 d[4] = {pack2(f0.x, f0.y), pack2(f0.z, f0.w),
                pack2(f1.x, f1.y), pack2(f1.z, f1.w)};
    *(bf16x8*)(x1b + i) = *(bf16x8*)d;
  } else if (b < 2560) {
    const int rel = b - 2048;                     // Wqkv: R=1024 C=2048, 32x16
    const int bx = rel & 31, by = rel >> 5;
    cvtT_body(Wqkv, WqT, 1024, 2048, bx, by, bx < 16 ? cfac : 1.0f, tid);
  } else if (b < 2816) {
    const int rel = b - 2560;                     // Wproj: R=C=1024, 16x16
    const int bx = rel & 15, by = rel >> 4;
    cvtT_body(Wproj, WpT, 1024, 1024, bx, by, 1.0f, tid);
  } else {
    const int rel = b - 2816;                     // x2: R=4096 C=1024, 16x64
    const int bx = rel & 15, by = rel >> 4;
    cvtT_body(x2, Vt, 4096, 1024, bx, by, 1.0f, tid);
  }
}

// QK = x1b(bf16 MxK) @ WqT(bf16 NxK)^T -> bf16. 128x128 tile + dbuf (R7).
__global__ __launch_bounds__(256) void gemm1_k(const u16* __restrict__ A,
                                               const u16* __restrict__ Bt,
                                               u16* __restrict__ C,
                                               int M, int N, int K) {
  __shared__ __align__(16) u16 As[2][128 * 64];
  __shared__ __align__(16) u16 Bs[2][128 * 64];
  const int tid = threadIdx.x;
  const int wave = tid >> 6, lane = tid & 63;
  const int quad = lane >> 4, l16 = lane & 15;
  const int m0 = blockIdx.y * 128, n0 = blockIdx.x * 128;
  const int wm = wave * 32;
  const int lrow = lane >> 3, lc8 = (lane & 7) * 8;

  f32x4 acc[2][8] = {};
#pragma unroll
  for (int c = 0; c < 4; ++c) {
    const int cw = wave * 4 + c;
    g2l16(A + (m0 + cw * 8 + lrow) * K + lc8, (char*)As[0] + cw * 1024);
    g2l16(Bt + (n0 + cw * 8 + lrow) * K + lc8, (char*)Bs[0] + cw * 1024);
  }
  const int NIT = K / 64;
  for (int it = 0; it < NIT; ++it) {
    const int cur = it & 1;
    __syncthreads();
    if (it + 1 < NIT) {
      const int k0 = (it + 1) * 64;
#pragma unroll
      for (int c = 0; c < 4; ++c) {
        const int cw = wave * 4 + c;
        g2l16(A + (m0 + cw * 8 + lrow) * K + k0 + lc8, (char*)As[1 - cur] + cw * 1024);
        g2l16(Bt + (n0 + cw * 8 + lrow) * K + k0 + lc8, (char*)Bs[1 - cur] + cw * 1024);
      }
    }
#pragma unroll
    for (int ks = 0; ks < 2; ++ks) {
      bf16x8 a[2], b[8];
#pragma unroll
      for (int mt = 0; mt < 2; ++mt)
        a[mt] = *(const bf16x8*)(As[cur] + (wm + mt * 16 + l16) * 64 + ks * 32 + quad * 8);
#pragma unroll
      for (int nt = 0; nt < 8; ++nt)
        b[nt] = *(const bf16x8*)(Bs[cur] + (nt * 16 + l16) * 64 + ks * 32 + quad * 8);
#pragma unroll
      for (int mt = 0; mt < 2; ++mt)
#pragma unroll
        for (int nt = 0; nt < 8; ++nt)
          acc[mt][nt] = mfma16(a[mt], b[nt], acc[mt][nt]);
    }
  }
#pragma unroll
  for (int mt = 0; mt < 2; ++mt)
#pragma unroll
    for (int nt = 0; nt < 8; ++nt)
#pragma unroll
      for (int r = 0; r < 4; ++r)
        C[(m0 + wm + mt * 16 + quad * 4 + r) * N + n0 + nt * 16 + l16] =
            f2bf(acc[mt][nt][r]);
}

// out = Obf(bf16 MxK) @ WpT(bf16 NxK)^T + bias(f32) -> f32. 128x64, dbuf.
__global__ __launch_bounds__(256) void gemm2_k(const u16* __restrict__ A,
                                               const u16* __restrict__ Bt,
                                               float* __restrict__ C,
                                               const float* __restrict__ bias,
                                               int M, int N, int K) {
  __shared__ __align__(16) u16 As[2][128 * 64];
  __shared__ __align__(16) u16 Bs[2][64 * 64];
  const int tid = threadIdx.x;
  const int wave = tid >> 6, lane = tid & 63;
  const int quad = lane >> 4, l16 = lane & 15;
  const int m0 = blockIdx.y * 128, n0 = blockIdx.x * 64;
  const int wm = wave * 32;
  const int lrow = lane >> 3, lc8 = (lane & 7) * 8;

  f32x4 acc[2][4] = {};
#pragma unroll
  for (int c = 0; c < 4; ++c) {
    const int cw = wave * 4 + c;
    g2l16(A + (m0 + cw * 8 + lrow) * K + lc8, (char*)As[0] + cw * 1024);
  }
#pragma unroll
  for (int c = 0; c < 2; ++c) {
    const int cw = wave * 2 + c;
    g2l16(Bt + (n0 + cw * 8 + lrow) * K + lc8, (char*)Bs[0] + cw * 1024);
  }
  const int NIT = K / 64;
  for (int it = 0; it < NIT; ++it) {
    const int cur = it & 1;
    __syncthreads();
    if (it + 1 < NIT) {
      const int k0 = (it + 1) * 64;
#pragma unroll
      for (int c = 0; c < 4; ++c) {
        const int cw = wave * 4 + c;
        g2l16(A + (m0 + cw * 8 + lrow) * K + k0 + lc8, (char*)As[1 - cur] + cw * 1024);
      }
#pragma unroll
      for (int c = 0; c < 2; ++c) {
        const int cw = wave * 2 + c;
        g2l16(Bt + (n0 + cw * 8 + lrow) * K + k0 + lc8, (char*)Bs[1 - cur] + cw * 1024);
      }
    }
#pragma unroll
    for (int ks = 0; ks < 2; ++ks) {
      bf16x8 a[2], b[4];
#pragma unroll
      for (int mt = 0; mt < 2; ++mt)
        a[mt] = *(const bf16x8*)(As[cur] + (wm + mt * 16 + l16) * 64 + ks * 32 + quad * 8);
#pragma unroll
      for (int nt = 0; nt < 4; ++nt)
        b[nt] = *(const bf16x8*)(Bs[cur] + (nt * 16 + l16) * 64 + ks * 32 + quad * 8);
#pragma unroll
      for (int mt = 0; mt < 2; ++mt)
#pragma unroll
        for (int nt = 0; nt < 4; ++nt)
          acc[mt][nt] = mfma16(a[mt], b[nt], acc[mt][nt]);
    }
  }
#pragma unroll
  for (int mt = 0; mt < 2; ++mt)
#pragma unroll
    for (int nt = 0; nt < 4; ++nt)
#pragma unroll
      for (int r = 0; r < 4; ++r) {
        const int col = n0 + nt * 16 + l16;
        C[(m0 + wm + mt * 16 + quad * 4 + r) * N + col] = acc[mt][nt][r] + bias[col];
      }
}

// Flash attention v10: L2-DIRECT K/V — no K/V LDS staging, NO BARRIERS.
// K/V fragments are read straight from global (per-XCD working set = active
// head's K+V ~1.5MB << 4MB L2; staged version's FETCH_SIZE=70MB proves L2
// already absorbs the re-reads). Fragment addresses verified algebraically
// equal to the staged path's effective addresses (LDS chunk c8 held global
// chunk c8^(row&7); the frag-read XOR cancels it -> plain ks*32+quad*8; each
// K head-slice is one aligned 128B line fully consumed by 4 quads x 2 ks).
// Removes: all __syncthreads (lockstep root cause; kernel is now barrier-free
// and race-free by construction), K/V staging, 16/20 LDS reads per tile, K/V
// bank conflicts. P path (wave-private LDS, lgkm-ordered), softmax, Q-load,
// epilogue: byte-identical to R2/R7-verified v6b.
// CONVICTED (do not reintroduce): 8-wave remap (R3/R4 race), s_setprio (R5
// +7us), subtile pairing (R6 +6us), split-KV+comb (R9 net +2us).
__global__ __launch_bounds__(256) void attn_k(const u16* __restrict__ QK,
                                              const u16* __restrict__ Vt,
                                              u16* __restrict__ O) {
  __shared__ __align__(16) u16 Ps[4][32 * 64];  // per-wave [q][key] bf16, swizzled
  const int tid = threadIdx.x;
  const int wave = tid >> 6, lane = tid & 63;
  const int quad = lane >> 4, l16 = lane & 15;
  const int head = blockIdx.y;
  const int qb = blockIdx.x * 128 + wave * 32;
  const int swz = (quad ^ (l16 & 7)) * 8;  // P-buffer swizzle base (ks=0)

  bf16x8 qf[2][2];
#pragma unroll
  for (int mt = 0; mt < 2; ++mt)
#pragma unroll
    for (int ks = 0; ks < 2; ++ks)
      qf[mt][ks] = *(const bf16x8*)(QK + (qb + mt * 16 + l16) * 2048 + head * 64 +
                                    ks * 32 + quad * 8);

  // ones B-fragment for row-sum MFMA (register-built, alignment-safe)
  union { u32x4 u; bf16x8 b; } OU;
  OU.u = (u32x4){0x3F803F80u, 0x3F803F80u, 0x3F803F80u, 0x3F803F80u};
  const bf16x8 onesf = OU.b;

  // K base: row stride 2048 elems; head slice = one aligned 128B line/row.
  const u16* Kg = QK + CDIM + head * 64;
  // V base: Vt is [d][key], row stride NSEQ; rows head*64..head*64+63.
  const u16* Vg = Vt + (head * 64) * NSEQ;

  f32x4 o[2][4] = {};
  f32x4 ol[2] = {};  // row-sums: ol[mt][r] = sum over keys for row quad*4+r
  u16* Pw = Ps[wave];

  for (int kt = 0; kt < NSEQ / 64; ++kt) {
    const u16* Kt = Kg + kt * (64 * 2048);
    const u16* Vc = Vg + kt * 64;

    f32x4 s[2][4] = {};
#pragma unroll
    for (int ks = 0; ks < 2; ++ks)
#pragma unroll
      for (int nt = 0; nt < 4; ++nt) {
        const bf16x8 kf =
            *(const bf16x8*)(Kt + (nt * 16 + l16) * 2048 + ks * 32 + quad * 8);
#pragma unroll
        for (int mt = 0; mt < 2; ++mt)
          s[mt][nt] = mfma16(kf, qf[mt][ks], s[mt][nt]);
      }

#pragma unroll
    for (int mt = 0; mt < 2; ++mt)
#pragma unroll
      for (int nt = 0; nt < 4; ++nt) {
        const float p0 = fexp2(s[mt][nt][0]);
        const float p1 = fexp2(s[mt][nt][1]);
        const float p2 = fexp2(s[mt][nt][2]);
        const float p3 = fexp2(s[mt][nt][3]);
        u32 d01 = pack2(p0, p1), d23 = pack2(p2, p3);
        const int col8 = (nt * 2 + (quad >> 1)) ^ (l16 & 7);
        u32* dst = (u32*)(Pw + (mt * 16 + l16) * 64 + col8 * 8 + (quad & 1) * 4);
        dst[0] = d01; dst[1] = d23;  // ds_write_b64
      }

#pragma unroll
    for (int ks = 0; ks < 2; ++ks) {
      bf16x8 pf[2];
#pragma unroll
      for (int mt = 0; mt < 2; ++mt)
        pf[mt] = *(const bf16x8*)(Pw + (mt * 16 + l16) * 64 + (swz ^ (ks * 32)));
#pragma unroll
      for (int dt = 0; dt < 4; ++dt) {
        const bf16x8 vf =
            *(const bf16x8*)(Vc + (dt * 16 + l16) * NSEQ + ks * 32 + quad * 8);
#pragma unroll
        for (int mt = 0; mt < 2; ++mt)
          o[mt][dt] = mfma16(pf[mt], vf, o[mt][dt]);
      }
#pragma unroll
      for (int mt = 0; mt < 2; ++mt)
        ol[mt] = mfma16(pf[mt], onesf, ol[mt]);  // row-sum accumulate
    }
  }

  // o and ol share the same A-fragment (pf), hence the same C/D row mapping:
  // ol[mt][r] is the row-sum for the exact row o[mt][*][r] holds. No shuffles.
#pragma unroll
  for (int mt = 0; mt < 2; ++mt)
#pragma unroll
    for (int r = 0; r < 4; ++r) {
      const float lv = 1.0f / ol[mt][r];
#pragma unroll
      for (int dt = 0; dt < 4; ++dt)
        O[(qb + mt * 16 + quad * 4 + r) * CDIM + head * 64 + dt * 16 + l16] =
            f2bf(o[mt][dt][r] * lv);
    }
}

extern "C" void kernel_launch(void* const* d_in, const int* in_sizes, int n_in,
                              void* d_out, int out_size, void* d_ws, size_t ws_size,
                              hipStream_t stream) {
  const float* x1    = (const float*)d_in[0];  // 4096x1024 f32
  const float* x2    = (const float*)d_in[1];  // 4096x1024 f32
  const float* Wqkv  = (const float*)d_in[2];  // 1024x2048 f32
  const float* Wproj = (const float*)d_in[3];  // 1024x1024 f32
  const float* bproj = (const float*)d_in[4];  // 1024 f32
  float* out = (float*)d_out;                  // 4096x1024 f32

  char* ws = (char*)d_ws;
  u16* QK  = (u16*)(ws);                      // 4096x2048 bf16 (16MB)
  u16* Vt  = (u16*)(ws + 16u * 1024 * 1024);  // 1024x4096 bf16 (8MB)
  u16* Obf = (u16*)(ws + 24u * 1024 * 1024);  // 4096x1024 bf16 (8MB)
  u16* WpT = (u16*)(ws + 32u * 1024 * 1024);  // 1024x1024 bf16 (2MB)
  u16* WqT = (u16*)(ws + 34u * 1024 * 1024);  // 2048x1024 bf16 (4MB)
  u16* x1b = (u16*)(ws + 38u * 1024 * 1024);  // 4096x1024 bf16 (8MB)

  const float cfac = SCALE * LOG2E;  // softmax scale folded into q-cols of Wqkv

  prep_k<<<dim3(3840), 256, 0, stream>>>(x1, x1b, Wqkv, WqT, Wproj, WpT, x2, Vt,
                                         cfac);
  gemm1_k<<<dim3(2048 / 128, 4096 / 128), 256, 0, stream>>>(x1b, WqT, QK,
                                                            4096, 2048, 1024);
  attn_k<<<dim3(4096 / 128, HNUM), 256, 0, stream>>>(QK, Vt, Obf);
  gemm2_k<<<dim3(1024 / 64, 4096 / 128), 256, 0, stream>>>(Obf, WpT, out, bproj,
                                                           4096, 1024, 1024);
}

// Round 11
// 238.994 us; speedup vs baseline: 1.8386x; 1.8386x over previous
//
#include <hip/hip_runtime.h>

typedef unsigned short u16;
typedef unsigned int u32;

#define HNUM 16
#define NSEQ 4096
#define CDIM 1024
#define SCALE 0.125f
#define LOG2E 1.4426950408889634f

using bf16x8 = __attribute__((ext_vector_type(8))) __bf16;
using f32x4  = __attribute__((ext_vector_type(4))) float;
using u32x4  = __attribute__((ext_vector_type(4))) u32;

__device__ __forceinline__ u16 f2bf(float f) {
  union { float f; u32 u; } v; v.f = f;
  u32 u = v.u;
  return (u16)((u + 0x7fffu + ((u >> 16) & 1u)) >> 16);
}
__device__ __forceinline__ float fexp2(float x) { return __builtin_amdgcn_exp2f(x); }

__device__ __forceinline__ f32x4 mfma16(bf16x8 a, bf16x8 b, f32x4 c) {
  return __builtin_amdgcn_mfma_f32_16x16x32_bf16(a, b, c, 0, 0, 0);
}

// pack 2 f32 -> 1 dword of 2 bf16 (round-half-up): lo16=bf(a), hi16=bf(b)
__device__ __forceinline__ u32 pack2(float a, float b) {
  union { float f; u32 u; } A, B;
  A.f = a; B.f = b;
  return __builtin_amdgcn_perm(B.u + 0x8000u, A.u + 0x8000u, 0x07060302u);
}

// async global->LDS, 16B/lane; LDS dest = wave-uniform base + lane*16
__device__ __forceinline__ void g2l16(const void* g, void* l) {
  __builtin_amdgcn_global_load_lds(
      (const __attribute__((address_space(1))) unsigned int*)(unsigned long long)g,
      (__attribute__((address_space(3))) unsigned int*)(unsigned int)(unsigned long long)l,
      16, 0, 0);
}

// ---- merged prep kernel: x1 cvt + 3 convert-transposes, range-dispatched ----
__device__ __forceinline__ void cvtT_body(const float* __restrict__ in,
                                          u16* __restrict__ out, int R, int C,
                                          int bx, int by, float scale, int tid) {
  __shared__ u16 t[64][65];
  const int r0 = by * 64, c0 = bx * 64;
  const int tr = tid >> 2, tc = (tid & 3) * 16;
  const float* src = in + (r0 + tr) * C + c0 + tc;
#pragma unroll
  for (int i = 0; i < 16; ++i) t[tr][tc + i] = f2bf(src[i] * scale);
  __syncthreads();
  u16* dst = out + (c0 + tr) * R + r0 + tc;
#pragma unroll
  for (int i = 0; i < 16; ++i) dst[i] = t[tc + i][tr];
}

// blocks: [0,2048) x1 cvt | [2048,2560) Wqkv T | [2560,2816) Wproj T | [2816,3840) x2 T
__global__ __launch_bounds__(256) void prep_k(const float* __restrict__ x1,
                                              u16* __restrict__ x1b,
                                              const float* __restrict__ Wqkv,
                                              u16* __restrict__ WqT,
                                              const float* __restrict__ Wproj,
                                              u16* __restrict__ WpT,
                                              const float* __restrict__ x2,
                                              u16* __restrict__ Vt,
                                              float cfac) {
  const int b = blockIdx.x, tid = threadIdx.x;
  if (b < 2048) {
    const int i = (b * 256 + tid) * 8;
    const float4 f0 = *(const float4*)(x1 + i);
    const float4 f1 = *(const float4*)(x1 + i + 4);
    u32 d[4] = {pack2(f0.x, f0.y), pack2(f0.z, f0.w),
                pack2(f1.x, f1.y), pack2(f1.z, f1.w)};
    *(bf16x8*)(x1b + i) = *(bf16x8*)d;
  } else if (b < 2560) {
    const int rel = b - 2048;                     // Wqkv: R=1024 C=2048, 32x16
    const int bx = rel & 31, by = rel >> 5;
    cvtT_body(Wqkv, WqT, 1024, 2048, bx, by, bx < 16 ? cfac : 1.0f, tid);
  } else if (b < 2816) {
    const int rel = b - 2560;                     // Wproj: R=C=1024, 16x16
    const int bx = rel & 15, by = rel >> 4;
    cvtT_body(Wproj, WpT, 1024, 1024, bx, by, 1.0f, tid);
  } else {
    const int rel = b - 2816;                     // x2: R=4096 C=1024, 16x64
    const int bx = rel & 15, by = rel >> 4;
    cvtT_body(x2, Vt, 4096, 1024, bx, by, 1.0f, tid);
  }
}

// QK = x1b(bf16 MxK) @ WqT(bf16 NxK)^T -> bf16. 128x128 tile + dbuf (R7).
__global__ __launch_bounds__(256) void gemm1_k(const u16* __restrict__ A,
                                               const u16* __restrict__ Bt,
                                               u16* __restrict__ C,
                                               int M, int N, int K) {
  __shared__ __align__(16) u16 As[2][128 * 64];
  __shared__ __align__(16) u16 Bs[2][128 * 64];
  const int tid = threadIdx.x;
  const int wave = tid >> 6, lane = tid & 63;
  const int quad = lane >> 4, l16 = lane & 15;
  const int m0 = blockIdx.y * 128, n0 = blockIdx.x * 128;
  const int wm = wave * 32;
  const int lrow = lane >> 3, lc8 = (lane & 7) * 8;

  f32x4 acc[2][8] = {};
#pragma unroll
  for (int c = 0; c < 4; ++c) {
    const int cw = wave * 4 + c;
    g2l16(A + (m0 + cw * 8 + lrow) * K + lc8, (char*)As[0] + cw * 1024);
    g2l16(Bt + (n0 + cw * 8 + lrow) * K + lc8, (char*)Bs[0] + cw * 1024);
  }
  const int NIT = K / 64;
  for (int it = 0; it < NIT; ++it) {
    const int cur = it & 1;
    __syncthreads();
    if (it + 1 < NIT) {
      const int k0 = (it + 1) * 64;
#pragma unroll
      for (int c = 0; c < 4; ++c) {
        const int cw = wave * 4 + c;
        g2l16(A + (m0 + cw * 8 + lrow) * K + k0 + lc8, (char*)As[1 - cur] + cw * 1024);
        g2l16(Bt + (n0 + cw * 8 + lrow) * K + k0 + lc8, (char*)Bs[1 - cur] + cw * 1024);
      }
    }
#pragma unroll
    for (int ks = 0; ks < 2; ++ks) {
      bf16x8 a[2], b[8];
#pragma unroll
      for (int mt = 0; mt < 2; ++mt)
        a[mt] = *(const bf16x8*)(As[cur] + (wm + mt * 16 + l16) * 64 + ks * 32 + quad * 8);
#pragma unroll
      for (int nt = 0; nt < 8; ++nt)
        b[nt] = *(const bf16x8*)(Bs[cur] + (nt * 16 + l16) * 64 + ks * 32 + quad * 8);
#pragma unroll
      for (int mt = 0; mt < 2; ++mt)
#pragma unroll
        for (int nt = 0; nt < 8; ++nt)
          acc[mt][nt] = mfma16(a[mt], b[nt], acc[mt][nt]);
    }
  }
#pragma unroll
  for (int mt = 0; mt < 2; ++mt)
#pragma unroll
    for (int nt = 0; nt < 8; ++nt)
#pragma unroll
      for (int r = 0; r < 4; ++r)
        C[(m0 + wm + mt * 16 + quad * 4 + r) * N + n0 + nt * 16 + l16] =
            f2bf(acc[mt][nt][r]);
}

// out = Obf(bf16 MxK) @ WpT(bf16 NxK)^T + bias(f32) -> f32. 128x64, dbuf.
__global__ __launch_bounds__(256) void gemm2_k(const u16* __restrict__ A,
                                               const u16* __restrict__ Bt,
                                               float* __restrict__ C,
                                               const float* __restrict__ bias,
                                               int M, int N, int K) {
  __shared__ __align__(16) u16 As[2][128 * 64];
  __shared__ __align__(16) u16 Bs[2][64 * 64];
  const int tid = threadIdx.x;
  const int wave = tid >> 6, lane = tid & 63;
  const int quad = lane >> 4, l16 = lane & 15;
  const int m0 = blockIdx.y * 128, n0 = blockIdx.x * 64;
  const int wm = wave * 32;
  const int lrow = lane >> 3, lc8 = (lane & 7) * 8;

  f32x4 acc[2][4] = {};
#pragma unroll
  for (int c = 0; c < 4; ++c) {
    const int cw = wave * 4 + c;
    g2l16(A + (m0 + cw * 8 + lrow) * K + lc8, (char*)As[0] + cw * 1024);
  }
#pragma unroll
  for (int c = 0; c < 2; ++c) {
    const int cw = wave * 2 + c;
    g2l16(Bt + (n0 + cw * 8 + lrow) * K + lc8, (char*)Bs[0] + cw * 1024);
  }
  const int NIT = K / 64;
  for (int it = 0; it < NIT; ++it) {
    const int cur = it & 1;
    __syncthreads();
    if (it + 1 < NIT) {
      const int k0 = (it + 1) * 64;
#pragma unroll
      for (int c = 0; c < 4; ++c) {
        const int cw = wave * 4 + c;
        g2l16(A + (m0 + cw * 8 + lrow) * K + k0 + lc8, (char*)As[1 - cur] + cw * 1024);
      }
#pragma unroll
      for (int c = 0; c < 2; ++c) {
        const int cw = wave * 2 + c;
        g2l16(Bt + (n0 + cw * 8 + lrow) * K + k0 + lc8, (char*)Bs[1 - cur] + cw * 1024);
      }
    }
#pragma unroll
    for (int ks = 0; ks < 2; ++ks) {
      bf16x8 a[2], b[4];
#pragma unroll
      for (int mt = 0; mt < 2; ++mt)
        a[mt] = *(const bf16x8*)(As[cur] + (wm + mt * 16 + l16) * 64 + ks * 32 + quad * 8);
#pragma unroll
      for (int nt = 0; nt < 4; ++nt)
        b[nt] = *(const bf16x8*)(Bs[cur] + (nt * 16 + l16) * 64 + ks * 32 + quad * 8);
#pragma unroll
      for (int mt = 0; mt < 2; ++mt)
#pragma unroll
        for (int nt = 0; nt < 4; ++nt)
          acc[mt][nt] = mfma16(a[mt], b[nt], acc[mt][nt]);
    }
  }
#pragma unroll
  for (int mt = 0; mt < 2; ++mt)
#pragma unroll
    for (int nt = 0; nt < 4; ++nt)
#pragma unroll
      for (int r = 0; r < 4; ++r) {
        const int col = n0 + nt * 16 + l16;
        C[(m0 + wm + mt * 16 + quad * 4 + r) * N + col] = acc[mt][nt][r] + bias[col];
      }
}

// Flash attention v11: v6b compute body (R2/R7-verified, byte-identical) with
// the barrier DRAIN removed: 3-buffer ring, prefetch distance 2, counted
// vmcnt + raw s_barrier (T4 / m201 pattern; vmcnt FIFO semantics per m135).
// Per iter k:  vmcnt(4)  -> own stage(k) loads done (issued 2 iters ago,
//                           already landed => near-zero wait)
//              s_barrier -> ALL waves' stage(k) landed (publish-safe)
//              issue stage(k+2) into buf computed in iter k-1 (WAR-safe:
//                           every wave passed the barrier after computing it)
//              compute buf(k%3)
// Unlike __syncthreads (s_waitcnt vmcnt(0) before s_barrier), fresh
// prefetches stay in flight across the barrier. Last iter waits vmcnt(0).
// CONVICTED (do not reintroduce): 8-wave remap (R3/R4 race), s_setprio (R5
// +7us), subtile pairing (R6 +6us), split-KV+comb (R9 +2us), L2-direct K/V
// (R10 +205us — VMEM address path, 16 lines/instr).
__global__ __launch_bounds__(256) void attn_k(const u16* __restrict__ QK,
                                              const u16* __restrict__ Vt,
                                              u16* __restrict__ O) {
  __shared__ __align__(16) u16 Ks[3][64 * 64];  // [ring][key][d], swizzled
  __shared__ __align__(16) u16 Vs[3][64 * 64];  // [ring][d][key], swizzled
  __shared__ __align__(16) u16 Ps[4][32 * 64];  // per-wave [q][key] bf16, swizzled
  const int tid = threadIdx.x;
  const int wave = tid >> 6, lane = tid & 63;
  const int quad = lane >> 4, l16 = lane & 15;
  const int head = blockIdx.y;
  const int qb = blockIdx.x * 128 + wave * 32;
  const int lrow = lane >> 3;               // staging row within 8-row chunk
  const int lc8 = ((lane & 7) ^ lrow) * 8;  // staging logical col (u16 units)
  const int swz = (quad ^ (l16 & 7)) * 8;   // frag-read swizzle base (ks=0)

  // 8 chunks of 1KB each for Ks and Vs, 2 chunks per wave (shared staging)
  const u16* kp[2];
  const u16* vp[2];
#pragma unroll
  for (int c = 0; c < 2; ++c) {
    const int row = (wave * 2 + c) * 8 + lrow;
    kp[c] = QK + row * 2048 + CDIM + head * 64 + lc8;  // +64*2048 per tile
    vp[c] = Vt + (head * 64 + row) * NSEQ + lc8;       // +64 per tile
  }

  bf16x8 qf[2][2];
#pragma unroll
  for (int mt = 0; mt < 2; ++mt)
#pragma unroll
    for (int ks = 0; ks < 2; ++ks)
      qf[mt][ks] = *(const bf16x8*)(QK + (qb + mt * 16 + l16) * 2048 + head * 64 +
                                    ks * 32 + quad * 8);

  // ones B-fragment for row-sum MFMA (register-built, alignment-safe)
  union { u32x4 u; bf16x8 b; } OU;
  OU.u = (u32x4){0x3F803F80u, 0x3F803F80u, 0x3F803F80u, 0x3F803F80u};
  const bf16x8 onesf = OU.b;

  f32x4 o[2][4] = {};
  f32x4 ol[2] = {};  // row-sums: ol[mt][r] = sum over keys for row quad*4+r
  u16* Pw = Ps[wave];

  // prologue: stage tiles 0 and 1 into ring slots 0 and 1
#pragma unroll
  for (int s = 0; s < 2; ++s)
#pragma unroll
    for (int c = 0; c < 2; ++c) {
      const int cw = wave * 2 + c;
      g2l16(kp[c], (char*)Ks[s] + cw * 1024);
      g2l16(vp[c], (char*)Vs[s] + cw * 1024);
      kp[c] += 64 * 2048;
      vp[c] += 64;
    }

  const int NIT = NSEQ / 64;
  int cur = 0;
  for (int kt = 0; kt < NIT; ++kt) {
    // Wait own stage(kt) (oldest 4 of ≤8 outstanding), NOT the fresh prefetch.
    if (kt < NIT - 1)
      asm volatile("s_waitcnt vmcnt(4)" ::: "memory");
    else
      asm volatile("s_waitcnt vmcnt(0)" ::: "memory");
    __builtin_amdgcn_s_barrier();       // raw: no vmcnt drain
    __builtin_amdgcn_sched_barrier(0);  // pin: nothing crosses this point

    if (kt + 2 < NIT) {
      int nxt = cur + 2;
      if (nxt >= 3) nxt -= 3;
#pragma unroll
      for (int c = 0; c < 2; ++c) {
        const int cw = wave * 2 + c;
        g2l16(kp[c], (char*)Ks[nxt] + cw * 1024);
        g2l16(vp[c], (char*)Vs[nxt] + cw * 1024);
        kp[c] += 64 * 2048;
        vp[c] += 64;
      }
    }

    const u16* Kc = Ks[cur];
    const u16* Vc = Vs[cur];

    f32x4 s[2][4] = {};
#pragma unroll
    for (int ks = 0; ks < 2; ++ks)
#pragma unroll
      for (int nt = 0; nt < 4; ++nt) {
        const bf16x8 kf =
            *(const bf16x8*)(Kc + (nt * 16 + l16) * 64 + (swz ^ (ks * 32)));
#pragma unroll
        for (int mt = 0; mt < 2; ++mt)
          s[mt][nt] = mfma16(kf, qf[mt][ks], s[mt][nt]);
      }

#pragma unroll
    for (int mt = 0; mt < 2; ++mt)
#pragma unroll
      for (int nt = 0; nt < 4; ++nt) {
        const float p0 = fexp2(s[mt][nt][0]);
        const float p1 = fexp2(s[mt][nt][1]);
        const float p2 = fexp2(s[mt][nt][2]);
        const float p3 = fexp2(s[mt][nt][3]);
        u32 d01 = pack2(p0, p1), d23 = pack2(p2, p3);
        const int col8 = (nt * 2 + (quad >> 1)) ^ (l16 & 7);
        u32* dst = (u32*)(Pw + (mt * 16 + l16) * 64 + col8 * 8 + (quad & 1) * 4);
        dst[0] = d01; dst[1] = d23;  // ds_write_b64
      }

#pragma unroll
    for (int ks = 0; ks < 2; ++ks) {
      bf16x8 pf[2];
#pragma unroll
      for (int mt = 0; mt < 2; ++mt)
        pf[mt] = *(const bf16x8*)(Pw + (mt * 16 + l16) * 64 + (swz ^ (ks * 32)));
#pragma unroll
      for (int dt = 0; dt < 4; ++dt) {
        const bf16x8 vf =
            *(const bf16x8*)(Vc + (dt * 16 + l16) * 64 + (swz ^ (ks * 32)));
#pragma unroll
        for (int mt = 0; mt < 2; ++mt)
          o[mt][dt] = mfma16(pf[mt], vf, o[mt][dt]);
      }
#pragma unroll
      for (int mt = 0; mt < 2; ++mt)
        ol[mt] = mfma16(pf[mt], onesf, ol[mt]);  // row-sum accumulate
    }

    cur = (cur == 2) ? 0 : cur + 1;
  }

  // o and ol share the same A-fragment (pf), hence the same C/D row mapping:
  // ol[mt][r] is the row-sum for the exact row o[mt][*][r] holds. No shuffles.
#pragma unroll
  for (int mt = 0; mt < 2; ++mt)
#pragma unroll
    for (int r = 0; r < 4; ++r) {
      const float lv = 1.0f / ol[mt][r];
#pragma unroll
      for (int dt = 0; dt < 4; ++dt)
        O[(qb + mt * 16 + quad * 4 + r) * CDIM + head * 64 + dt * 16 + l16] =
            f2bf(o[mt][dt][r] * lv);
    }
}

extern "C" void kernel_launch(void* const* d_in, const int* in_sizes, int n_in,
                              void* d_out, int out_size, void* d_ws, size_t ws_size,
                              hipStream_t stream) {
  const float* x1    = (const float*)d_in[0];  // 4096x1024 f32
  const float* x2    = (const float*)d_in[1];  // 4096x1024 f32
  const float* Wqkv  = (const float*)d_in[2];  // 1024x2048 f32
  const float* Wproj = (const float*)d_in[3];  // 1024x1024 f32
  const float* bproj = (const float*)d_in[4];  // 1024 f32
  float* out = (float*)d_out;                  // 4096x1024 f32

  char* ws = (char*)d_ws;
  u16* QK  = (u16*)(ws);                      // 4096x2048 bf16 (16MB)
  u16* Vt  = (u16*)(ws + 16u * 1024 * 1024);  // 1024x4096 bf16 (8MB)
  u16* Obf = (u16*)(ws + 24u * 1024 * 1024);  // 4096x1024 bf16 (8MB)
  u16* WpT = (u16*)(ws + 32u * 1024 * 1024);  // 1024x1024 bf16 (2MB)
  u16* WqT = (u16*)(ws + 34u * 1024 * 1024);  // 2048x1024 bf16 (4MB)
  u16* x1b = (u16*)(ws + 38u * 1024 * 1024);  // 4096x1024 bf16 (8MB)

  const float cfac = SCALE * LOG2E;  // softmax scale folded into q-cols of Wqkv

  prep_k<<<dim3(3840), 256, 0, stream>>>(x1, x1b, Wqkv, WqT, Wproj, WpT, x2, Vt,
                                         cfac);
  gemm1_k<<<dim3(2048 / 128, 4096 / 128), 256, 0, stream>>>(x1b, WqT, QK,
                                                            4096, 2048, 1024);
  attn_k<<<dim3(4096 / 128, HNUM), 256, 0, stream>>>(QK, Vt, Obf);
  gemm2_k<<<dim3(1024 / 64, 4096 / 128), 256, 0, stream>>>(Obf, WpT, out, bproj,
                                                           4096, 1024, 1024);
}

// Round 12
// 236.960 us; speedup vs baseline: 1.8543x; 1.0086x over previous
//
#include <hip/hip_runtime.h>

typedef unsigned short u16;
typedef unsigned int u32;

#define HNUM 16
#define NSEQ 4096
#define CDIM 1024
#define SCALE 0.125f
#define LOG2E 1.4426950408889634f

using bf16x8 = __attribute__((ext_vector_type(8))) __bf16;
using f32x4  = __attribute__((ext_vector_type(4))) float;
using u32x4  = __attribute__((ext_vector_type(4))) u32;

__device__ __forceinline__ u16 f2bf(float f) {
  union { float f; u32 u; } v; v.f = f;
  u32 u = v.u;
  return (u16)((u + 0x7fffu + ((u >> 16) & 1u)) >> 16);
}
__device__ __forceinline__ float fexp2(float x) { return __builtin_amdgcn_exp2f(x); }

__device__ __forceinline__ f32x4 mfma16(bf16x8 a, bf16x8 b, f32x4 c) {
  return __builtin_amdgcn_mfma_f32_16x16x32_bf16(a, b, c, 0, 0, 0);
}

// pack 2 f32 -> 1 dword of 2 bf16 (round-half-up): lo16=bf(a), hi16=bf(b)
__device__ __forceinline__ u32 pack2(float a, float b) {
  union { float f; u32 u; } A, B;
  A.f = a; B.f = b;
  return __builtin_amdgcn_perm(B.u + 0x8000u, A.u + 0x8000u, 0x07060302u);
}

// async global->LDS, 16B/lane; LDS dest = wave-uniform base + lane*16
__device__ __forceinline__ void g2l16(const void* g, void* l) {
  __builtin_amdgcn_global_load_lds(
      (const __attribute__((address_space(1))) unsigned int*)(unsigned long long)g,
      (__attribute__((address_space(3))) unsigned int*)(unsigned int)(unsigned long long)l,
      16, 0, 0);
}

// ---- merged prep kernel: x1 cvt + 3 convert-transposes, range-dispatched ----
__device__ __forceinline__ void cvtT_body(const float* __restrict__ in,
                                          u16* __restrict__ out, int R, int C,
                                          int bx, int by, float scale, int tid) {
  __shared__ u16 t[64][65];
  const int r0 = by * 64, c0 = bx * 64;
  const int tr = tid >> 2, tc = (tid & 3) * 16;
  const float* src = in + (r0 + tr) * C + c0 + tc;
#pragma unroll
  for (int i = 0; i < 16; ++i) t[tr][tc + i] = f2bf(src[i] * scale);
  __syncthreads();
  u16* dst = out + (c0 + tr) * R + r0 + tc;
#pragma unroll
  for (int i = 0; i < 16; ++i) dst[i] = t[tc + i][tr];
}

// blocks: [0,2048) x1 cvt | [2048,2560) Wqkv T | [2560,2816) Wproj T | [2816,3840) x2 T
__global__ __launch_bounds__(256) void prep_k(const float* __restrict__ x1,
                                              u16* __restrict__ x1b,
                                              const float* __restrict__ Wqkv,
                                              u16* __restrict__ WqT,
                                              const float* __restrict__ Wproj,
                                              u16* __restrict__ WpT,
                                              const float* __restrict__ x2,
                                              u16* __restrict__ Vt,
                                              float cfac) {
  const int b = blockIdx.x, tid = threadIdx.x;
  if (b < 2048) {
    const int i = (b * 256 + tid) * 8;
    const float4 f0 = *(const float4*)(x1 + i);
    const float4 f1 = *(const float4*)(x1 + i + 4);
    u32 d[4] = {pack2(f0.x, f0.y), pack2(f0.z, f0.w),
                pack2(f1.x, f1.y), pack2(f1.z, f1.w)};
    *(bf16x8*)(x1b + i) = *(bf16x8*)d;
  } else if (b < 2560) {
    const int rel = b - 2048;                     // Wqkv: R=1024 C=2048, 32x16
    const int bx = rel & 31, by = rel >> 5;
    cvtT_body(Wqkv, WqT, 1024, 2048, bx, by, bx < 16 ? cfac : 1.0f, tid);
  } else if (b < 2816) {
    const int rel = b - 2560;                     // Wproj: R=C=1024, 16x16
    const int bx = rel & 15, by = rel >> 4;
    cvtT_body(Wproj, WpT, 1024, 1024, bx, by, 1.0f, tid);
  } else {
    const int rel = b - 2816;                     // x2: R=4096 C=1024, 16x64
    const int bx = rel & 15, by = rel >> 4;
    cvtT_body(x2, Vt, 4096, 1024, bx, by, 1.0f, tid);
  }
}

// QK = x1b(bf16 MxK) @ WqT(bf16 NxK)^T -> bf16. 128x128 tile + dbuf (R7).
__global__ __launch_bounds__(256) void gemm1_k(const u16* __restrict__ A,
                                               const u16* __restrict__ Bt,
                                               u16* __restrict__ C,
                                               int M, int N, int K) {
  __shared__ __align__(16) u16 As[2][128 * 64];
  __shared__ __align__(16) u16 Bs[2][128 * 64];
  const int tid = threadIdx.x;
  const int wave = tid >> 6, lane = tid & 63;
  const int quad = lane >> 4, l16 = lane & 15;
  const int m0 = blockIdx.y * 128, n0 = blockIdx.x * 128;
  const int wm = wave * 32;
  const int lrow = lane >> 3, lc8 = (lane & 7) * 8;

  f32x4 acc[2][8] = {};
#pragma unroll
  for (int c = 0; c < 4; ++c) {
    const int cw = wave * 4 + c;
    g2l16(A + (m0 + cw * 8 + lrow) * K + lc8, (char*)As[0] + cw * 1024);
    g2l16(Bt + (n0 + cw * 8 + lrow) * K + lc8, (char*)Bs[0] + cw * 1024);
  }
  const int NIT = K / 64;
  for (int it = 0; it < NIT; ++it) {
    const int cur = it & 1;
    __syncthreads();
    if (it + 1 < NIT) {
      const int k0 = (it + 1) * 64;
#pragma unroll
      for (int c = 0; c < 4; ++c) {
        const int cw = wave * 4 + c;
        g2l16(A + (m0 + cw * 8 + lrow) * K + k0 + lc8, (char*)As[1 - cur] + cw * 1024);
        g2l16(Bt + (n0 + cw * 8 + lrow) * K + k0 + lc8, (char*)Bs[1 - cur] + cw * 1024);
      }
    }
#pragma unroll
    for (int ks = 0; ks < 2; ++ks) {
      bf16x8 a[2], b[8];
#pragma unroll
      for (int mt = 0; mt < 2; ++mt)
        a[mt] = *(const bf16x8*)(As[cur] + (wm + mt * 16 + l16) * 64 + ks * 32 + quad * 8);
#pragma unroll
      for (int nt = 0; nt < 8; ++nt)
        b[nt] = *(const bf16x8*)(Bs[cur] + (nt * 16 + l16) * 64 + ks * 32 + quad * 8);
#pragma unroll
      for (int mt = 0; mt < 2; ++mt)
#pragma unroll
        for (int nt = 0; nt < 8; ++nt)
          acc[mt][nt] = mfma16(a[mt], b[nt], acc[mt][nt]);
    }
  }
#pragma unroll
  for (int mt = 0; mt < 2; ++mt)
#pragma unroll
    for (int nt = 0; nt < 8; ++nt)
#pragma unroll
      for (int r = 0; r < 4; ++r)
        C[(m0 + wm + mt * 16 + quad * 4 + r) * N + n0 + nt * 16 + l16] =
            f2bf(acc[mt][nt][r]);
}

// out = Obf(bf16 MxK) @ WpT(bf16 NxK)^T + bias(f32) -> f32. 128x64, dbuf.
__global__ __launch_bounds__(256) void gemm2_k(const u16* __restrict__ A,
                                               const u16* __restrict__ Bt,
                                               float* __restrict__ C,
                                               const float* __restrict__ bias,
                                               int M, int N, int K) {
  __shared__ __align__(16) u16 As[2][128 * 64];
  __shared__ __align__(16) u16 Bs[2][64 * 64];
  const int tid = threadIdx.x;
  const int wave = tid >> 6, lane = tid & 63;
  const int quad = lane >> 4, l16 = lane & 15;
  const int m0 = blockIdx.y * 128, n0 = blockIdx.x * 64;
  const int wm = wave * 32;
  const int lrow = lane >> 3, lc8 = (lane & 7) * 8;

  f32x4 acc[2][4] = {};
#pragma unroll
  for (int c = 0; c < 4; ++c) {
    const int cw = wave * 4 + c;
    g2l16(A + (m0 + cw * 8 + lrow) * K + lc8, (char*)As[0] + cw * 1024);
  }
#pragma unroll
  for (int c = 0; c < 2; ++c) {
    const int cw = wave * 2 + c;
    g2l16(Bt + (n0 + cw * 8 + lrow) * K + lc8, (char*)Bs[0] + cw * 1024);
  }
  const int NIT = K / 64;
  for (int it = 0; it < NIT; ++it) {
    const int cur = it & 1;
    __syncthreads();
    if (it + 1 < NIT) {
      const int k0 = (it + 1) * 64;
#pragma unroll
      for (int c = 0; c < 4; ++c) {
        const int cw = wave * 4 + c;
        g2l16(A + (m0 + cw * 8 + lrow) * K + k0 + lc8, (char*)As[1 - cur] + cw * 1024);
      }
#pragma unroll
      for (int c = 0; c < 2; ++c) {
        const int cw = wave * 2 + c;
        g2l16(Bt + (n0 + cw * 8 + lrow) * K + k0 + lc8, (char*)Bs[1 - cur] + cw * 1024);
      }
    }
#pragma unroll
    for (int ks = 0; ks < 2; ++ks) {
      bf16x8 a[2], b[4];
#pragma unroll
      for (int mt = 0; mt < 2; ++mt)
        a[mt] = *(const bf16x8*)(As[cur] + (wm + mt * 16 + l16) * 64 + ks * 32 + quad * 8);
#pragma unroll
      for (int nt = 0; nt < 4; ++nt)
        b[nt] = *(const bf16x8*)(Bs[cur] + (nt * 16 + l16) * 64 + ks * 32 + quad * 8);
#pragma unroll
      for (int mt = 0; mt < 2; ++mt)
#pragma unroll
        for (int nt = 0; nt < 4; ++nt)
          acc[mt][nt] = mfma16(a[mt], b[nt], acc[mt][nt]);
    }
  }
#pragma unroll
  for (int mt = 0; mt < 2; ++mt)
#pragma unroll
    for (int nt = 0; nt < 4; ++nt)
#pragma unroll
      for (int r = 0; r < 4; ++r) {
        const int col = n0 + nt * 16 + l16;
        C[(m0 + wm + mt * 16 + quad * 4 + r) * N + col] = acc[mt][nt][r] + bias[col];
      }
}

// Flash attention v12: R11 ring (3-buffer, prefetch distance 2, counted vmcnt
// + raw s_barrier) with ONE change: sched_barrier(0) REMOVED (m141-class
// order-pinning poison — R11: VALUBusy 43->51, attn 107->121). Replaced by a
// zero-instruction compiler memory fence after s_barrier, which is all that's
// needed: it stops g2l16 hoisting above the barrier (WAR on ring slot), while
// leaving the instruction scheduler free. LDS WAR window is otherwise closed:
// every ds_read of tile k-1 is consumed by an MFMA (compiler lgkmcnt) before
// the wave reaches barrier k; P buffer is wave-private. Ring mechanics
// correctness-verified on HW in R11 (absmax 9.77e-4).
// CONVICTED (do not reintroduce): 8-wave remap (R3/R4 race), s_setprio (R5
// +7us), subtile pairing (R6 +6us), split-KV+comb (R9 +2us), L2-direct K/V
// (R10 +205us), sched_barrier(0) order-pinning (R11 +13us).
__global__ __launch_bounds__(256) void attn_k(const u16* __restrict__ QK,
                                              const u16* __restrict__ Vt,
                                              u16* __restrict__ O) {
  __shared__ __align__(16) u16 Ks[3][64 * 64];  // [ring][key][d], swizzled
  __shared__ __align__(16) u16 Vs[3][64 * 64];  // [ring][d][key], swizzled
  __shared__ __align__(16) u16 Ps[4][32 * 64];  // per-wave [q][key] bf16, swizzled
  const int tid = threadIdx.x;
  const int wave = tid >> 6, lane = tid & 63;
  const int quad = lane >> 4, l16 = lane & 15;
  const int head = blockIdx.y;
  const int qb = blockIdx.x * 128 + wave * 32;
  const int lrow = lane >> 3;               // staging row within 8-row chunk
  const int lc8 = ((lane & 7) ^ lrow) * 8;  // staging logical col (u16 units)
  const int swz = (quad ^ (l16 & 7)) * 8;   // frag-read swizzle base (ks=0)

  // 8 chunks of 1KB each for Ks and Vs, 2 chunks per wave (shared staging)
  const u16* kp[2];
  const u16* vp[2];
#pragma unroll
  for (int c = 0; c < 2; ++c) {
    const int row = (wave * 2 + c) * 8 + lrow;
    kp[c] = QK + row * 2048 + CDIM + head * 64 + lc8;  // +64*2048 per tile
    vp[c] = Vt + (head * 64 + row) * NSEQ + lc8;       // +64 per tile
  }

  bf16x8 qf[2][2];
#pragma unroll
  for (int mt = 0; mt < 2; ++mt)
#pragma unroll
    for (int ks = 0; ks < 2; ++ks)
      qf[mt][ks] = *(const bf16x8*)(QK + (qb + mt * 16 + l16) * 2048 + head * 64 +
                                    ks * 32 + quad * 8);

  // ones B-fragment for row-sum MFMA (register-built, alignment-safe)
  union { u32x4 u; bf16x8 b; } OU;
  OU.u = (u32x4){0x3F803F80u, 0x3F803F80u, 0x3F803F80u, 0x3F803F80u};
  const bf16x8 onesf = OU.b;

  f32x4 o[2][4] = {};
  f32x4 ol[2] = {};  // row-sums: ol[mt][r] = sum over keys for row quad*4+r
  u16* Pw = Ps[wave];

  // prologue: stage tiles 0 and 1 into ring slots 0 and 1
#pragma unroll
  for (int s = 0; s < 2; ++s)
#pragma unroll
    for (int c = 0; c < 2; ++c) {
      const int cw = wave * 2 + c;
      g2l16(kp[c], (char*)Ks[s] + cw * 1024);
      g2l16(vp[c], (char*)Vs[s] + cw * 1024);
      kp[c] += 64 * 2048;
      vp[c] += 64;
    }

  const int NIT = NSEQ / 64;
  int cur = 0;
  for (int kt = 0; kt < NIT; ++kt) {
    // Wait own stage(kt) (oldest 4 of ≤8 outstanding), NOT the fresh prefetch.
    if (kt < NIT - 1)
      asm volatile("s_waitcnt vmcnt(4)" ::: "memory");
    else
      asm volatile("s_waitcnt vmcnt(0)" ::: "memory");
    __builtin_amdgcn_s_barrier();        // raw: no vmcnt drain
    asm volatile("" ::: "memory");       // compiler fence only: g2l16 below
                                         // cannot hoist above the barrier

    if (kt + 2 < NIT) {
      int nxt = cur + 2;
      if (nxt >= 3) nxt -= 3;
#pragma unroll
      for (int c = 0; c < 2; ++c) {
        const int cw = wave * 2 + c;
        g2l16(kp[c], (char*)Ks[nxt] + cw * 1024);
        g2l16(vp[c], (char*)Vs[nxt] + cw * 1024);
        kp[c] += 64 * 2048;
        vp[c] += 64;
      }
    }

    const u16* Kc = Ks[cur];
    const u16* Vc = Vs[cur];

    f32x4 s[2][4] = {};
#pragma unroll
    for (int ks = 0; ks < 2; ++ks)
#pragma unroll
      for (int nt = 0; nt < 4; ++nt) {
        const bf16x8 kf =
            *(const bf16x8*)(Kc + (nt * 16 + l16) * 64 + (swz ^ (ks * 32)));
#pragma unroll
        for (int mt = 0; mt < 2; ++mt)
          s[mt][nt] = mfma16(kf, qf[mt][ks], s[mt][nt]);
      }

#pragma unroll
    for (int mt = 0; mt < 2; ++mt)
#pragma unroll
      for (int nt = 0; nt < 4; ++nt) {
        const float p0 = fexp2(s[mt][nt][0]);
        const float p1 = fexp2(s[mt][nt][1]);
        const float p2 = fexp2(s[mt][nt][2]);
        const float p3 = fexp2(s[mt][nt][3]);
        u32 d01 = pack2(p0, p1), d23 = pack2(p2, p3);
        const int col8 = (nt * 2 + (quad >> 1)) ^ (l16 & 7);
        u32* dst = (u32*)(Pw + (mt * 16 + l16) * 64 + col8 * 8 + (quad & 1) * 4);
        dst[0] = d01; dst[1] = d23;  // ds_write_b64
      }

#pragma unroll
    for (int ks = 0; ks < 2; ++ks) {
      bf16x8 pf[2];
#pragma unroll
      for (int mt = 0; mt < 2; ++mt)
        pf[mt] = *(const bf16x8*)(Pw + (mt * 16 + l16) * 64 + (swz ^ (ks * 32)));
#pragma unroll
      for (int dt = 0; dt < 4; ++dt) {
        const bf16x8 vf =
            *(const bf16x8*)(Vc + (dt * 16 + l16) * 64 + (swz ^ (ks * 32)));
#pragma unroll
        for (int mt = 0; mt < 2; ++mt)
          o[mt][dt] = mfma16(pf[mt], vf, o[mt][dt]);
      }
#pragma unroll
      for (int mt = 0; mt < 2; ++mt)
        ol[mt] = mfma16(pf[mt], onesf, ol[mt]);  // row-sum accumulate
    }

    cur = (cur == 2) ? 0 : cur + 1;
  }

  // o and ol share the same A-fragment (pf), hence the same C/D row mapping:
  // ol[mt][r] is the row-sum for the exact row o[mt][*][r] holds. No shuffles.
#pragma unroll
  for (int mt = 0; mt < 2; ++mt)
#pragma unroll
    for (int r = 0; r < 4; ++r) {
      const float lv = 1.0f / ol[mt][r];
#pragma unroll
      for (int dt = 0; dt < 4; ++dt)
        O[(qb + mt * 16 + quad * 4 + r) * CDIM + head * 64 + dt * 16 + l16] =
            f2bf(o[mt][dt][r] * lv);
    }
}

extern "C" void kernel_launch(void* const* d_in, const int* in_sizes, int n_in,
                              void* d_out, int out_size, void* d_ws, size_t ws_size,
                              hipStream_t stream) {
  const float* x1    = (const float*)d_in[0];  // 4096x1024 f32
  const float* x2    = (const float*)d_in[1];  // 4096x1024 f32
  const float* Wqkv  = (const float*)d_in[2];  // 1024x2048 f32
  const float* Wproj = (const float*)d_in[3];  // 1024x1024 f32
  const float* bproj = (const float*)d_in[4];  // 1024 f32
  float* out = (float*)d_out;                  // 4096x1024 f32

  char* ws = (char*)d_ws;
  u16* QK  = (u16*)(ws);                      // 4096x2048 bf16 (16MB)
  u16* Vt  = (u16*)(ws + 16u * 1024 * 1024);  // 1024x4096 bf16 (8MB)
  u16* Obf = (u16*)(ws + 24u * 1024 * 1024);  // 4096x1024 bf16 (8MB)
  u16* WpT = (u16*)(ws + 32u * 1024 * 1024);  // 1024x1024 bf16 (2MB)
  u16* WqT = (u16*)(ws + 34u * 1024 * 1024);  // 2048x1024 bf16 (4MB)
  u16* x1b = (u16*)(ws + 38u * 1024 * 1024);  // 4096x1024 bf16 (8MB)

  const float cfac = SCALE * LOG2E;  // softmax scale folded into q-cols of Wqkv

  prep_k<<<dim3(3840), 256, 0, stream>>>(x1, x1b, Wqkv, WqT, Wproj, WpT, x2, Vt,
                                         cfac);
  gemm1_k<<<dim3(2048 / 128, 4096 / 128), 256, 0, stream>>>(x1b, WqT, QK,
                                                            4096, 2048, 1024);
  attn_k<<<dim3(4096 / 128, HNUM), 256, 0, stream>>>(QK, Vt, Obf);
  gemm2_k<<<dim3(1024 / 64, 4096 / 128), 256, 0, stream>>>(Obf, WpT, out, bproj,
                                                           4096, 1024, 1024);
}

// Round 13
// 227.189 us; speedup vs baseline: 1.9341x; 1.0430x over previous
//
#include <hip/hip_runtime.h>

typedef unsigned short u16;
typedef unsigned int u32;

#define HNUM 16
#define NSEQ 4096
#define CDIM 1024
#define SCALE 0.125f
#define LOG2E 1.4426950408889634f

using bf16x8 = __attribute__((ext_vector_type(8))) __bf16;
using f32x4  = __attribute__((ext_vector_type(4))) float;
using u32x4  = __attribute__((ext_vector_type(4))) u32;

__device__ __forceinline__ u16 f2bf(float f) {
  union { float f; u32 u; } v; v.f = f;
  u32 u = v.u;
  return (u16)((u + 0x7fffu + ((u >> 16) & 1u)) >> 16);
}
__device__ __forceinline__ float fexp2(float x) { return __builtin_amdgcn_exp2f(x); }

__device__ __forceinline__ f32x4 mfma16(bf16x8 a, bf16x8 b, f32x4 c) {
  return __builtin_amdgcn_mfma_f32_16x16x32_bf16(a, b, c, 0, 0, 0);
}

// pack 2 f32 -> 1 dword of 2 bf16 (round-half-up): lo16=bf(a), hi16=bf(b)
__device__ __forceinline__ u32 pack2(float a, float b) {
  union { float f; u32 u; } A, B;
  A.f = a; B.f = b;
  return __builtin_amdgcn_perm(B.u + 0x8000u, A.u + 0x8000u, 0x07060302u);
}

// async global->LDS, 16B/lane; LDS dest = wave-uniform base + lane*16
__device__ __forceinline__ void g2l16(const void* g, void* l) {
  __builtin_amdgcn_global_load_lds(
      (const __attribute__((address_space(1))) unsigned int*)(unsigned long long)g,
      (__attribute__((address_space(3))) unsigned int*)(unsigned int)(unsigned long long)l,
      16, 0, 0);
}

// ---- merged prep kernel: x1 cvt + 3 convert-transposes, range-dispatched ----
// R13: vectorized — float4 global loads (16 scalar -> 4 vec) and b128 global
// stores (16 scalar u16 -> 2 vec, 16B-aligned since R%8==0 and tc%16==0).
__device__ __forceinline__ void cvtT_body(const float* __restrict__ in,
                                          u16* __restrict__ out, int R, int C,
                                          int bx, int by, float scale, int tid) {
  __shared__ u16 t[64][65];
  const int r0 = by * 64, c0 = bx * 64;
  const int tr = tid >> 2, tc = (tid & 3) * 16;
  const float* src = in + (r0 + tr) * C + c0 + tc;
#pragma unroll
  for (int i = 0; i < 4; ++i) {
    const float4 f = *(const float4*)(src + i * 4);
    t[tr][tc + i * 4 + 0] = f2bf(f.x * scale);
    t[tr][tc + i * 4 + 1] = f2bf(f.y * scale);
    t[tr][tc + i * 4 + 2] = f2bf(f.z * scale);
    t[tr][tc + i * 4 + 3] = f2bf(f.w * scale);
  }
  __syncthreads();
  u16* dst = out + (c0 + tr) * R + r0 + tc;
#pragma unroll
  for (int v = 0; v < 2; ++v) {
    u16 tmp[8];
#pragma unroll
    for (int i = 0; i < 8; ++i) tmp[i] = t[tc + v * 8 + i][tr];
    *(bf16x8*)(dst + v * 8) = *(bf16x8*)tmp;
  }
}

// blocks: [0,2048) x1 cvt | [2048,2560) Wqkv T | [2560,2816) Wproj T | [2816,3840) x2 T
__global__ __launch_bounds__(256) void prep_k(const float* __restrict__ x1,
                                              u16* __restrict__ x1b,
                                              const float* __restrict__ Wqkv,
                                              u16* __restrict__ WqT,
                                              const float* __restrict__ Wproj,
                                              u16* __restrict__ WpT,
                                              const float* __restrict__ x2,
                                              u16* __restrict__ Vt,
                                              float cfac) {
  const int b = blockIdx.x, tid = threadIdx.x;
  if (b < 2048) {
    const int i = (b * 256 + tid) * 8;
    const float4 f0 = *(const float4*)(x1 + i);
    const float4 f1 = *(const float4*)(x1 + i + 4);
    u32 d[4] = {pack2(f0.x, f0.y), pack2(f0.z, f0.w),
                pack2(f1.x, f1.y), pack2(f1.z, f1.w)};
    *(bf16x8*)(x1b + i) = *(bf16x8*)d;
  } else if (b < 2560) {
    const int rel = b - 2048;                     // Wqkv: R=1024 C=2048, 32x16
    const int bx = rel & 31, by = rel >> 5;
    cvtT_body(Wqkv, WqT, 1024, 2048, bx, by, bx < 16 ? cfac : 1.0f, tid);
  } else if (b < 2816) {
    const int rel = b - 2560;                     // Wproj: R=C=1024, 16x16
    const int bx = rel & 15, by = rel >> 4;
    cvtT_body(Wproj, WpT, 1024, 1024, bx, by, 1.0f, tid);
  } else {
    const int rel = b - 2816;                     // x2: R=4096 C=1024, 16x64
    const int bx = rel & 15, by = rel >> 4;
    cvtT_body(x2, Vt, 4096, 1024, bx, by, 1.0f, tid);
  }
}

// QK = x1b(bf16 MxK) @ WqT(bf16 NxK)^T -> bf16. 128x128 tile + dbuf (R7).
__global__ __launch_bounds__(256) void gemm1_k(const u16* __restrict__ A,
                                               const u16* __restrict__ Bt,
                                               u16* __restrict__ C,
                                               int M, int N, int K) {
  __shared__ __align__(16) u16 As[2][128 * 64];
  __shared__ __align__(16) u16 Bs[2][128 * 64];
  const int tid = threadIdx.x;
  const int wave = tid >> 6, lane = tid & 63;
  const int quad = lane >> 4, l16 = lane & 15;
  const int m0 = blockIdx.y * 128, n0 = blockIdx.x * 128;
  const int wm = wave * 32;
  const int lrow = lane >> 3, lc8 = (lane & 7) * 8;

  f32x4 acc[2][8] = {};
#pragma unroll
  for (int c = 0; c < 4; ++c) {
    const int cw = wave * 4 + c;
    g2l16(A + (m0 + cw * 8 + lrow) * K + lc8, (char*)As[0] + cw * 1024);
    g2l16(Bt + (n0 + cw * 8 + lrow) * K + lc8, (char*)Bs[0] + cw * 1024);
  }
  const int NIT = K / 64;
  for (int it = 0; it < NIT; ++it) {
    const int cur = it & 1;
    __syncthreads();
    if (it + 1 < NIT) {
      const int k0 = (it + 1) * 64;
#pragma unroll
      for (int c = 0; c < 4; ++c) {
        const int cw = wave * 4 + c;
        g2l16(A + (m0 + cw * 8 + lrow) * K + k0 + lc8, (char*)As[1 - cur] + cw * 1024);
        g2l16(Bt + (n0 + cw * 8 + lrow) * K + k0 + lc8, (char*)Bs[1 - cur] + cw * 1024);
      }
    }
#pragma unroll
    for (int ks = 0; ks < 2; ++ks) {
      bf16x8 a[2], b[8];
#pragma unroll
      for (int mt = 0; mt < 2; ++mt)
        a[mt] = *(const bf16x8*)(As[cur] + (wm + mt * 16 + l16) * 64 + ks * 32 + quad * 8);
#pragma unroll
      for (int nt = 0; nt < 8; ++nt)
        b[nt] = *(const bf16x8*)(Bs[cur] + (nt * 16 + l16) * 64 + ks * 32 + quad * 8);
#pragma unroll
      for (int mt = 0; mt < 2; ++mt)
#pragma unroll
        for (int nt = 0; nt < 8; ++nt)
          acc[mt][nt] = mfma16(a[mt], b[nt], acc[mt][nt]);
    }
  }
#pragma unroll
  for (int mt = 0; mt < 2; ++mt)
#pragma unroll
    for (int nt = 0; nt < 8; ++nt)
#pragma unroll
      for (int r = 0; r < 4; ++r)
        C[(m0 + wm + mt * 16 + quad * 4 + r) * N + n0 + nt * 16 + l16] =
            f2bf(acc[mt][nt][r]);
}

// out = Obf(bf16 MxK) @ WpT(bf16 NxK)^T + bias(f32) -> f32. 128x64, dbuf.
__global__ __launch_bounds__(256) void gemm2_k(const u16* __restrict__ A,
                                               const u16* __restrict__ Bt,
                                               float* __restrict__ C,
                                               const float* __restrict__ bias,
                                               int M, int N, int K) {
  __shared__ __align__(16) u16 As[2][128 * 64];
  __shared__ __align__(16) u16 Bs[2][64 * 64];
  const int tid = threadIdx.x;
  const int wave = tid >> 6, lane = tid & 63;
  const int quad = lane >> 4, l16 = lane & 15;
  const int m0 = blockIdx.y * 128, n0 = blockIdx.x * 64;
  const int wm = wave * 32;
  const int lrow = lane >> 3, lc8 = (lane & 7) * 8;

  f32x4 acc[2][4] = {};
#pragma unroll
  for (int c = 0; c < 4; ++c) {
    const int cw = wave * 4 + c;
    g2l16(A + (m0 + cw * 8 + lrow) * K + lc8, (char*)As[0] + cw * 1024);
  }
#pragma unroll
  for (int c = 0; c < 2; ++c) {
    const int cw = wave * 2 + c;
    g2l16(Bt + (n0 + cw * 8 + lrow) * K + lc8, (char*)Bs[0] + cw * 1024);
  }
  const int NIT = K / 64;
  for (int it = 0; it < NIT; ++it) {
    const int cur = it & 1;
    __syncthreads();
    if (it + 1 < NIT) {
      const int k0 = (it + 1) * 64;
#pragma unroll
      for (int c = 0; c < 4; ++c) {
        const int cw = wave * 4 + c;
        g2l16(A + (m0 + cw * 8 + lrow) * K + k0 + lc8, (char*)As[1 - cur] + cw * 1024);
      }
#pragma unroll
      for (int c = 0; c < 2; ++c) {
        const int cw = wave * 2 + c;
        g2l16(Bt + (n0 + cw * 8 + lrow) * K + k0 + lc8, (char*)Bs[1 - cur] + cw * 1024);
      }
    }
#pragma unroll
    for (int ks = 0; ks < 2; ++ks) {
      bf16x8 a[2], b[4];
#pragma unroll
      for (int mt = 0; mt < 2; ++mt)
        a[mt] = *(const bf16x8*)(As[cur] + (wm + mt * 16 + l16) * 64 + ks * 32 + quad * 8);
#pragma unroll
      for (int nt = 0; nt < 4; ++nt)
        b[nt] = *(const bf16x8*)(Bs[cur] + (nt * 16 + l16) * 64 + ks * 32 + quad * 8);
#pragma unroll
      for (int mt = 0; mt < 2; ++mt)
#pragma unroll
        for (int nt = 0; nt < 4; ++nt)
          acc[mt][nt] = mfma16(a[mt], b[nt], acc[mt][nt]);
    }
  }
#pragma unroll
  for (int mt = 0; mt < 2; ++mt)
#pragma unroll
    for (int nt = 0; nt < 4; ++nt)
#pragma unroll
      for (int r = 0; r < 4; ++r) {
        const int col = n0 + nt * 16 + l16;
        C[(m0 + wm + mt * 16 + quad * 4 + r) * N + col] = acc[mt][nt][r] + bias[col];
      }
}

// Flash attention v6b (R2/R7-verified, byte-exact revert): 4 waves/block,
// 32 q-rows/wave, shared K/V staging, MFMA ones-B row-sums, pack2.
// CONVICTED (do not reintroduce without root-cause):
//  - 8-wave/16-row remap (R3/R4): nondeterministic output (tripwire).
//  - s_setprio around MFMA (R5): +7us (lockstep structure, T5 inapplicable).
//  - two-subtile-per-barrier pairing (R6): +6us.
//  - split-KV + combine (R9): attn -4 but combine +6, net +2us.
//  - L2-direct K/V, no LDS (R10): +205us (VMEM address path, 16 lines/instr).
//  - 3-buffer ring + counted vmcnt + raw barrier (R11/R12): +11us (ring
//    addressing VALU/VGPR cost > drain savings; drain is near-free at
//    prefetch distance 1 already). Barrier-drain theory dead for this shape.
__global__ __launch_bounds__(256) void attn_k(const u16* __restrict__ QK,
                                              const u16* __restrict__ Vt,
                                              u16* __restrict__ O) {
  __shared__ __align__(16) u16 Ks[2][64 * 64];  // [key][d], swizzled
  __shared__ __align__(16) u16 Vs[2][64 * 64];  // [d][key], swizzled
  __shared__ __align__(16) u16 Ps[4][32 * 64];  // per-wave [q][key] bf16, swizzled
  const int tid = threadIdx.x;
  const int wave = tid >> 6, lane = tid & 63;
  const int quad = lane >> 4, l16 = lane & 15;
  const int head = blockIdx.y;
  const int qb = blockIdx.x * 128 + wave * 32;
  const int lrow = lane >> 3;               // staging row within 8-row chunk
  const int lc8 = ((lane & 7) ^ lrow) * 8;  // staging logical col (u16 units)
  const int swz = (quad ^ (l16 & 7)) * 8;   // frag-read swizzle base (ks=0)

  // 8 chunks of 1KB each for Ks and Vs, 2 chunks per wave (shared staging)
  const u16* kp[2];
  const u16* vp[2];
#pragma unroll
  for (int c = 0; c < 2; ++c) {
    const int row = (wave * 2 + c) * 8 + lrow;
    kp[c] = QK + row * 2048 + CDIM + head * 64 + lc8;  // +64*2048 per iter
    vp[c] = Vt + (head * 64 + row) * NSEQ + lc8;       // +64 per iter
  }

  bf16x8 qf[2][2];
#pragma unroll
  for (int mt = 0; mt < 2; ++mt)
#pragma unroll
    for (int ks = 0; ks < 2; ++ks)
      qf[mt][ks] = *(const bf16x8*)(QK + (qb + mt * 16 + l16) * 2048 + head * 64 +
                                    ks * 32 + quad * 8);

  // ones B-fragment for row-sum MFMA (register-built, alignment-safe)
  union { u32x4 u; bf16x8 b; } OU;
  OU.u = (u32x4){0x3F803F80u, 0x3F803F80u, 0x3F803F80u, 0x3F803F80u};
  const bf16x8 onesf = OU.b;

  f32x4 o[2][4] = {};
  f32x4 ol[2] = {};  // row-sums: ol[mt][r] = sum over keys for row quad*4+r
  u16* Pw = Ps[wave];

#pragma unroll
  for (int c = 0; c < 2; ++c) {
    const int cw = wave * 2 + c;
    g2l16(kp[c], (char*)Ks[0] + cw * 1024);
    g2l16(vp[c], (char*)Vs[0] + cw * 1024);
    kp[c] += 64 * 2048;
    vp[c] += 64;
  }

  for (int kt = 0; kt < NSEQ / 64; ++kt) {
    const int cur = kt & 1;
    __syncthreads();  // publishes buf[cur] (drains vmcnt)

    if (kt < NSEQ / 64 - 1) {
#pragma unroll
      for (int c = 0; c < 2; ++c) {
        const int cw = wave * 2 + c;
        g2l16(kp[c], (char*)Ks[1 - cur] + cw * 1024);
        g2l16(vp[c], (char*)Vs[1 - cur] + cw * 1024);
        kp[c] += 64 * 2048;
        vp[c] += 64;
      }
    }

    const u16* Kc = Ks[cur];
    const u16* Vc = Vs[cur];

    f32x4 s[2][4] = {};
#pragma unroll
    for (int ks = 0; ks < 2; ++ks)
#pragma unroll
      for (int nt = 0; nt < 4; ++nt) {
        const bf16x8 kf =
            *(const bf16x8*)(Kc + (nt * 16 + l16) * 64 + (swz ^ (ks * 32)));
#pragma unroll
        for (int mt = 0; mt < 2; ++mt)
          s[mt][nt] = mfma16(kf, qf[mt][ks], s[mt][nt]);
      }

#pragma unroll
    for (int mt = 0; mt < 2; ++mt)
#pragma unroll
      for (int nt = 0; nt < 4; ++nt) {
        const float p0 = fexp2(s[mt][nt][0]);
        const float p1 = fexp2(s[mt][nt][1]);
        const float p2 = fexp2(s[mt][nt][2]);
        const float p3 = fexp2(s[mt][nt][3]);
        u32 d01 = pack2(p0, p1), d23 = pack2(p2, p3);
        const int col8 = (nt * 2 + (quad >> 1)) ^ (l16 & 7);
        u32* dst = (u32*)(Pw + (mt * 16 + l16) * 64 + col8 * 8 + (quad & 1) * 4);
        dst[0] = d01; dst[1] = d23;  // ds_write_b64
      }

#pragma unroll
    for (int ks = 0; ks < 2; ++ks) {
      bf16x8 pf[2];
#pragma unroll
      for (int mt = 0; mt < 2; ++mt)
        pf[mt] = *(const bf16x8*)(Pw + (mt * 16 + l16) * 64 + (swz ^ (ks * 32)));
#pragma unroll
      for (int dt = 0; dt < 4; ++dt) {
        const bf16x8 vf =
            *(const bf16x8*)(Vc + (dt * 16 + l16) * 64 + (swz ^ (ks * 32)));
#pragma unroll
        for (int mt = 0; mt < 2; ++mt)
          o[mt][dt] = mfma16(pf[mt], vf, o[mt][dt]);
      }
#pragma unroll
      for (int mt = 0; mt < 2; ++mt)
        ol[mt] = mfma16(pf[mt], onesf, ol[mt]);  // row-sum accumulate
    }
  }

  // o and ol share the same A-fragment (pf), hence the same C/D row mapping:
  // ol[mt][r] is the row-sum for the exact row o[mt][*][r] holds. No shuffles.
#pragma unroll
  for (int mt = 0; mt < 2; ++mt)
#pragma unroll
    for (int r = 0; r < 4; ++r) {
      const float lv = 1.0f / ol[mt][r];
#pragma unroll
      for (int dt = 0; dt < 4; ++dt)
        O[(qb + mt * 16 + quad * 4 + r) * CDIM + head * 64 + dt * 16 + l16] =
            f2bf(o[mt][dt][r] * lv);
    }
}

extern "C" void kernel_launch(void* const* d_in, const int* in_sizes, int n_in,
                              void* d_out, int out_size, void* d_ws, size_t ws_size,
                              hipStream_t stream) {
  const float* x1    = (const float*)d_in[0];  // 4096x1024 f32
  const float* x2    = (const float*)d_in[1];  // 4096x1024 f32
  const float* Wqkv  = (const float*)d_in[2];  // 1024x2048 f32
  const float* Wproj = (const float*)d_in[3];  // 1024x1024 f32
  const float* bproj = (const float*)d_in[4];  // 1024 f32
  float* out = (float*)d_out;                  // 4096x1024 f32

  char* ws = (char*)d_ws;
  u16* QK  = (u16*)(ws);                      // 4096x2048 bf16 (16MB)
  u16* Vt  = (u16*)(ws + 16u * 1024 * 1024);  // 1024x4096 bf16 (8MB)
  u16* Obf = (u16*)(ws + 24u * 1024 * 1024);  // 4096x1024 bf16 (8MB)
  u16* WpT = (u16*)(ws + 32u * 1024 * 1024);  // 1024x1024 bf16 (2MB)
  u16* WqT = (u16*)(ws + 34u * 1024 * 1024);  // 2048x1024 bf16 (4MB)
  u16* x1b = (u16*)(ws + 38u * 1024 * 1024);  // 4096x1024 bf16 (8MB)

  const float cfac = SCALE * LOG2E;  // softmax scale folded into q-cols of Wqkv

  prep_k<<<dim3(3840), 256, 0, stream>>>(x1, x1b, Wqkv, WqT, Wproj, WpT, x2, Vt,
                                         cfac);
  gemm1_k<<<dim3(2048 / 128, 4096 / 128), 256, 0, stream>>>(x1b, WqT, QK,
                                                            4096, 2048, 1024);
  attn_k<<<dim3(4096 / 128, HNUM), 256, 0, stream>>>(QK, Vt, Obf);
  gemm2_k<<<dim3(1024 / 64, 4096 / 128), 256, 0, stream>>>(Obf, WpT, out, bproj,
                                                           4096, 1024, 1024);
}